// Round 2
// baseline (623.484 us; speedup 1.0000x reference)
//
#include <hip/hip_runtime.h>

#define FEAT 128
#define N_CLS 10

// ---------------- init: deg=1 (self loop), colsum=0 ----------------
__global__ void k_init(int* deg, float* colsum, int n) {
    int i = blockIdx.x * blockDim.x + threadIdx.x;
    if (i < n) deg[i] = 1;
    if (i < FEAT) colsum[i] = 0.f;
}

// ---------------- histogram of dst (int32 edge list!) ----------------
__global__ void k_hist(const int* __restrict__ dst, int* deg, int E) {
    int e = blockIdx.x * blockDim.x + threadIdx.x;
    if (e < E) atomicAdd(&deg[dst[e]], 1);
}

// ---------------- single-block scan: off/cursor/dinv ----------------
__global__ __launch_bounds__(1024) void k_scan(const int* __restrict__ deg, int* off,
                                               int* cursor, float* dinv, int n) {
    __shared__ int lds[1024];
    int t = threadIdx.x;
    int C = (n + 1023) / 1024;
    int lo = t * C, hi = min(lo + C, n);
    int s = 0;
    for (int i = lo; i < hi; ++i) s += deg[i] - 1;   // incoming count (minus self loop)
    lds[t] = s;
    __syncthreads();
    for (int d = 1; d < 1024; d <<= 1) {
        int v = (t >= d) ? lds[t - d] : 0;
        __syncthreads();
        lds[t] += v;
        __syncthreads();
    }
    int base = lds[t] - s;  // exclusive prefix
    for (int i = lo; i < hi; ++i) {
        off[i] = base;
        cursor[i] = base;
        dinv[i] = rsqrtf((float)deg[i]);
        base += deg[i] - 1;
    }
    if (t == 1023) off[n] = lds[1023];
}

// ---------------- fill CSR (by dst), store src ----------------
__global__ void k_fill(const int* __restrict__ src, const int* __restrict__ dst,
                       int* cursor, int* csr, int E) {
    int e = blockIdx.x * blockDim.x + threadIdx.x;
    if (e < E) {
        int d = dst[e];
        int pos = atomicAdd(&cursor[d], 1);
        csr[pos] = src[e];
    }
}

// ---------------- fused dual GEMM: hs=(x@W)*dinv, xs=x@Ws+b+bs ----------------
// block 256, 64-row tile; per thread 8 rows x (4 W-cols + 4 Ws-cols)
// NOTE: xs may alias x (in-place): each block stages its 64 rows to LDS before
// any global write, and blocks only write their own rows.
__global__ __launch_bounds__(256) void k_gemm(
    const float* x, const float* __restrict__ W,
    const float* __restrict__ Ws, const float* __restrict__ b,
    const float* __restrict__ bs, const float* __restrict__ dinv,
    float* __restrict__ hs, float* xs, int n) {
    __shared__ float x_lds[64 * FEAT];
    int tid = threadIdx.x;
    int row0 = blockIdx.x * 64;

    // stage x tile (coalesced float4)
    int c4 = (tid & 31) * 4;
    int rl = tid >> 5;  // 0..7
    #pragma unroll
    for (int p = 0; p < 8; ++p) {
        int r = rl + p * 8;
        float4 v = make_float4(0.f, 0.f, 0.f, 0.f);
        if (row0 + r < n) v = *(const float4*)&x[(size_t)(row0 + r) * FEAT + c4];
        *(float4*)&x_lds[r * FEAT + c4] = v;
    }
    __syncthreads();

    int ct = tid & 31;  // cols ct*4 .. ct*4+3
    int rt = tid >> 5;  // rows rt*8 .. rt*8+7
    float accW[8][4], accS[8][4];
    #pragma unroll
    for (int i = 0; i < 8; ++i)
        #pragma unroll
        for (int j = 0; j < 4; ++j) { accW[i][j] = 0.f; accS[i][j] = 0.f; }

    const float* Wp = W + ct * 4;
    const float* Sp = Ws + ct * 4;
    for (int k = 0; k < FEAT; ++k) {
        float4 bw = *(const float4*)&Wp[(size_t)k * FEAT];
        float4 bv = *(const float4*)&Sp[(size_t)k * FEAT];
        float a[8];
        #pragma unroll
        for (int i = 0; i < 8; ++i) a[i] = x_lds[(rt * 8 + i) * FEAT + k];
        #pragma unroll
        for (int i = 0; i < 8; ++i) {
            accW[i][0] += a[i] * bw.x; accW[i][1] += a[i] * bw.y;
            accW[i][2] += a[i] * bw.z; accW[i][3] += a[i] * bw.w;
            accS[i][0] += a[i] * bv.x; accS[i][1] += a[i] * bv.y;
            accS[i][2] += a[i] * bv.z; accS[i][3] += a[i] * bv.w;
        }
    }

    float4 bb  = *(const float4*)&b[ct * 4];
    float4 bb2 = *(const float4*)&bs[ct * 4];
    float4 bias = make_float4(bb.x + bb2.x, bb.y + bb2.y, bb.z + bb2.z, bb.w + bb2.w);
    #pragma unroll
    for (int i = 0; i < 8; ++i) {
        int r = row0 + rt * 8 + i;
        if (r < n) {
            float dv = dinv[r];
            size_t o = (size_t)r * FEAT + ct * 4;
            float4 o1 = make_float4(accW[i][0] * dv, accW[i][1] * dv,
                                    accW[i][2] * dv, accW[i][3] * dv);
            *(float4*)&hs[o] = o1;
            float4 o2 = make_float4(accS[i][0] + bias.x, accS[i][1] + bias.y,
                                    accS[i][2] + bias.z, accS[i][3] + bias.w);
            *(float4*)&xs[o] = o2;
        }
    }
}

// ---------------- aggregation + skip + bias + relu (in place in xs) ----------------
// one wave per node, float2 per lane
__global__ __launch_bounds__(256) void k_agg(
    const float* __restrict__ hs, float* __restrict__ xs,
    const float* __restrict__ dinv, const int* __restrict__ off,
    const int* __restrict__ csr, int n) {
    int wave = (blockIdx.x * 256 + threadIdx.x) >> 6;
    int lane = threadIdx.x & 63;
    if (wave >= n) return;
    int node = wave;
    size_t o = (size_t)node * FEAT + lane * 2;
    float2 acc = *(const float2*)&hs[o];  // self loop contribution (pre-scaled)
    int s = off[node], e = off[node + 1];
    for (int j = s; j < e; ++j) {
        int u = csr[j];
        float2 v = *(const float2*)&hs[(size_t)u * FEAT + lane * 2];
        acc.x += v.x; acc.y += v.y;
    }
    float dv = dinv[node];
    float2 sk = *(const float2*)&xs[o];
    float2 out;
    out.x = fmaxf(fmaf(acc.x, dv, sk.x), 0.f);
    out.y = fmaxf(fmaf(acc.y, dv, sk.y), 0.f);
    *(float2*)&xs[o] = out;
}

// ---------------- column sum (block-reduced, atomics on 128 addrs) ----------------
__global__ __launch_bounds__(256) void k_colsum(const float* __restrict__ x2,
                                                float* colsum, int n) {
    __shared__ float lds[256];
    int tid = threadIdx.x;
    int f = tid & 127;
    int half = tid >> 7;
    float acc = 0.f;
    for (int r = blockIdx.x * 2 + half; r < n; r += gridDim.x * 2)
        acc += x2[(size_t)r * FEAT + f];
    lds[tid] = acc;
    __syncthreads();
    if (tid < 128) atomicAdd(&colsum[f], lds[f] + lds[f + 128]);
}

// ---------------- final: (colsum/n) @ Wc + bc ----------------
__global__ void k_final(const float* __restrict__ colsum, const float* __restrict__ Wc,
                        const float* __restrict__ bc, float* out, int n) {
    int c = threadIdx.x;
    if (c < N_CLS) {
        float acc = 0.f;
        for (int f = 0; f < FEAT; ++f) acc += colsum[f] * Wc[f * N_CLS + c];
        out[c] = acc / (float)n + bc[c];
    }
}

extern "C" void kernel_launch(void* const* d_in, const int* in_sizes, int n_in,
                              void* d_out, int out_size, void* d_ws, size_t ws_size,
                              hipStream_t stream) {
    const float* x   = (const float*)d_in[0];
    const int*   ei  = (const int*)d_in[1];   // harness passes integer inputs as int32
    const float* W1  = (const float*)d_in[2];
    const float* b1  = (const float*)d_in[3];
    const float* Ws1 = (const float*)d_in[4];
    const float* bs1 = (const float*)d_in[5];
    const float* W2  = (const float*)d_in[6];
    const float* b2  = (const float*)d_in[7];
    const float* Ws2 = (const float*)d_in[8];
    const float* bs2 = (const float*)d_in[9];
    const float* Wc  = (const float*)d_in[10];
    const float* bc  = (const float*)d_in[11];
    float* out = (float*)d_out;

    const int n = in_sizes[0] / FEAT;
    const int E = in_sizes[1] / 2;
    const int* src = ei;
    const int* dst = ei + E;

    // workspace carve-out (~55 MB total)
    char* w = (char*)d_ws;
    auto alloc = [&](size_t bytes) -> void* {
        void* p = (void*)w;
        w += (bytes + 255) & ~(size_t)255;
        return p;
    };
    int*   deg    = (int*)alloc((size_t)n * 4);
    int*   off    = (int*)alloc(((size_t)n + 1) * 4);
    int*   cursor = (int*)alloc((size_t)n * 4);
    int*   csr    = (int*)alloc((size_t)E * 4);
    float* dinv   = (float*)alloc((size_t)n * 4);
    float* colsum = (float*)alloc(FEAT * 4);
    float* A = (float*)alloc((size_t)n * FEAT * 4);  // hs (both layers)
    float* B = (float*)alloc((size_t)n * FEAT * 4);  // xs1 -> out1 -> xs2 -> out2

    // graph prep
    k_init<<<(n + 255) / 256, 256, 0, stream>>>(deg, colsum, n);
    k_hist<<<(E + 255) / 256, 256, 0, stream>>>(dst, deg, E);
    k_scan<<<1, 1024, 0, stream>>>(deg, off, cursor, dinv, n);
    k_fill<<<(E + 255) / 256, 256, 0, stream>>>(src, dst, cursor, csr, E);

    int gemm_grid = (n + 63) / 64;
    int agg_grid  = (n + 3) / 4;

    // layer 1
    k_gemm<<<gemm_grid, 256, 0, stream>>>(x, W1, Ws1, b1, bs1, dinv, A, B, n);
    k_agg<<<agg_grid, 256, 0, stream>>>(A, B, dinv, off, csr, n);
    // layer 2 (xs written in-place into B; safe per-block row ownership)
    k_gemm<<<gemm_grid, 256, 0, stream>>>(B, W2, Ws2, b2, bs2, dinv, A, B, n);
    k_agg<<<agg_grid, 256, 0, stream>>>(A, B, dinv, off, csr, n);

    // readout
    k_colsum<<<512, 256, 0, stream>>>(B, colsum, n);
    k_final<<<1, 64, 0, stream>>>(colsum, Wc, bc, out, n);
}

// Round 3
// 485.498 us; speedup vs baseline: 1.2842x; 1.2842x over previous
//
#include <hip/hip_runtime.h>

#define FEAT 128
#define N_CLS 10

// ---------------- init: deg=1 (self loop), colsum=0 ----------------
__global__ void k_init(int* deg, float* colsum, int n) {
    int i = blockIdx.x * blockDim.x + threadIdx.x;
    if (i < n) deg[i] = 1;
    if (i < FEAT) colsum[i] = 0.f;
}

// ---------------- histogram of dst (int32 edge list) ----------------
__global__ void k_hist(const int* __restrict__ dst, int* deg, int E) {
    int e = blockIdx.x * blockDim.x + threadIdx.x;
    if (e < E) atomicAdd(&deg[dst[e]], 1);
}

// ---------------- hierarchical scan, stage 1: per-block sums of (deg-1) ----------------
__global__ __launch_bounds__(256) void k_bsum(const int* __restrict__ deg,
                                              int* __restrict__ bsum, int n) {
    int i = blockIdx.x * 256 + threadIdx.x;
    int v = (i < n) ? (deg[i] - 1) : 0;
    #pragma unroll
    for (int d = 32; d; d >>= 1) v += __shfl_down(v, d, 64);
    __shared__ int ws[4];
    int lane = threadIdx.x & 63, wid = threadIdx.x >> 6;
    if (lane == 0) ws[wid] = v;
    __syncthreads();
    if (threadIdx.x == 0) bsum[blockIdx.x] = ws[0] + ws[1] + ws[2] + ws[3];
}

// ---------------- stage 2: exclusive scan of block sums (nb <= 256) ----------------
__global__ __launch_bounds__(256) void k_bscan(int* bsum, int nb) {
    __shared__ int lds[256];
    int t = threadIdx.x;
    int v = (t < nb) ? bsum[t] : 0;
    lds[t] = v;
    __syncthreads();
    #pragma unroll
    for (int d = 1; d < 256; d <<= 1) {
        int u = (t >= d) ? lds[t - d] : 0;
        __syncthreads();
        lds[t] += u;
        __syncthreads();
    }
    if (t < nb) bsum[t] = lds[t] - v;  // exclusive prefix
}

// ---------------- stage 3: block-local scan + offset -> off/cursor/dinv ----------------
__global__ __launch_bounds__(256) void k_write(const int* __restrict__ deg,
                                               const int* __restrict__ bsum,
                                               int* off, int* cursor, float* dinv,
                                               int n, int E) {
    __shared__ int lds[256];
    int t = threadIdx.x;
    int i = blockIdx.x * 256 + t;
    int v = (i < n) ? (deg[i] - 1) : 0;
    lds[t] = v;
    __syncthreads();
    #pragma unroll
    for (int d = 1; d < 256; d <<= 1) {
        int u = (t >= d) ? lds[t - d] : 0;
        __syncthreads();
        lds[t] += u;
        __syncthreads();
    }
    if (i < n) {
        int o = bsum[blockIdx.x] + (lds[t] - v);
        off[i] = o;
        cursor[i] = o;
        dinv[i] = rsqrtf((float)deg[i]);
    }
    if (i == n - 1) off[n] = E;  // every edge lands in [0,n): total incoming == E
}

// ---------------- fill CSR (by dst), store src ----------------
__global__ void k_fill(const int* __restrict__ src, const int* __restrict__ dst,
                       int* cursor, int* csr, int E) {
    int e = blockIdx.x * blockDim.x + threadIdx.x;
    if (e < E) {
        int d = dst[e];
        int pos = atomicAdd(&cursor[d], 1);
        csr[pos] = src[e];
    }
}

// ---------------- fused dual GEMM: hs=(x@W)*dinv, xs=x@Ws+b+bs ----------------
// block 256, 64-row tile; per thread 8 rows x (4 W-cols + 4 Ws-cols)
// NOTE: xs may alias x (in-place): each block stages its 64 rows to LDS before
// any global write, and blocks only write their own rows.
__global__ __launch_bounds__(256) void k_gemm(
    const float* x, const float* __restrict__ W,
    const float* __restrict__ Ws, const float* __restrict__ b,
    const float* __restrict__ bs, const float* __restrict__ dinv,
    float* __restrict__ hs, float* xs, int n) {
    __shared__ float x_lds[64 * FEAT];
    int tid = threadIdx.x;
    int row0 = blockIdx.x * 64;

    // stage x tile (coalesced float4)
    int c4 = (tid & 31) * 4;
    int rl = tid >> 5;  // 0..7
    #pragma unroll
    for (int p = 0; p < 8; ++p) {
        int r = rl + p * 8;
        float4 v = make_float4(0.f, 0.f, 0.f, 0.f);
        if (row0 + r < n) v = *(const float4*)&x[(size_t)(row0 + r) * FEAT + c4];
        *(float4*)&x_lds[r * FEAT + c4] = v;
    }
    __syncthreads();

    int ct = tid & 31;  // cols ct*4 .. ct*4+3
    int rt = tid >> 5;  // rows rt*8 .. rt*8+7
    float accW[8][4], accS[8][4];
    #pragma unroll
    for (int i = 0; i < 8; ++i)
        #pragma unroll
        for (int j = 0; j < 4; ++j) { accW[i][j] = 0.f; accS[i][j] = 0.f; }

    const float* Wp = W + ct * 4;
    const float* Sp = Ws + ct * 4;
    for (int k = 0; k < FEAT; ++k) {
        float4 bw = *(const float4*)&Wp[(size_t)k * FEAT];
        float4 bv = *(const float4*)&Sp[(size_t)k * FEAT];
        float a[8];
        #pragma unroll
        for (int i = 0; i < 8; ++i) a[i] = x_lds[(rt * 8 + i) * FEAT + k];
        #pragma unroll
        for (int i = 0; i < 8; ++i) {
            accW[i][0] += a[i] * bw.x; accW[i][1] += a[i] * bw.y;
            accW[i][2] += a[i] * bw.z; accW[i][3] += a[i] * bw.w;
            accS[i][0] += a[i] * bv.x; accS[i][1] += a[i] * bv.y;
            accS[i][2] += a[i] * bv.z; accS[i][3] += a[i] * bv.w;
        }
    }

    float4 bb  = *(const float4*)&b[ct * 4];
    float4 bb2 = *(const float4*)&bs[ct * 4];
    float4 bias = make_float4(bb.x + bb2.x, bb.y + bb2.y, bb.z + bb2.z, bb.w + bb2.w);
    #pragma unroll
    for (int i = 0; i < 8; ++i) {
        int r = row0 + rt * 8 + i;
        if (r < n) {
            float dv = dinv[r];
            size_t o = (size_t)r * FEAT + ct * 4;
            float4 o1 = make_float4(accW[i][0] * dv, accW[i][1] * dv,
                                    accW[i][2] * dv, accW[i][3] * dv);
            *(float4*)&hs[o] = o1;
            float4 o2 = make_float4(accS[i][0] + bias.x, accS[i][1] + bias.y,
                                    accS[i][2] + bias.z, accS[i][3] + bias.w);
            *(float4*)&xs[o] = o2;
        }
    }
}

// ---------------- aggregation + skip + bias + relu (in place in xs) ----------------
// one wave per node, float2 per lane
__global__ __launch_bounds__(256) void k_agg(
    const float* __restrict__ hs, float* __restrict__ xs,
    const float* __restrict__ dinv, const int* __restrict__ off,
    const int* __restrict__ csr, int n) {
    int wave = (blockIdx.x * 256 + threadIdx.x) >> 6;
    int lane = threadIdx.x & 63;
    if (wave >= n) return;
    int node = wave;
    size_t o = (size_t)node * FEAT + lane * 2;
    float2 acc = *(const float2*)&hs[o];  // self loop contribution (pre-scaled)
    int s = off[node], e = off[node + 1];
    for (int j = s; j < e; ++j) {
        int u = csr[j];
        float2 v = *(const float2*)&hs[(size_t)u * FEAT + lane * 2];
        acc.x += v.x; acc.y += v.y;
    }
    float dv = dinv[node];
    float2 sk = *(const float2*)&xs[o];
    float2 out;
    out.x = fmaxf(fmaf(acc.x, dv, sk.x), 0.f);
    out.y = fmaxf(fmaf(acc.y, dv, sk.y), 0.f);
    *(float2*)&xs[o] = out;
}

// ---------------- column sum (block-reduced, atomics on 128 addrs) ----------------
__global__ __launch_bounds__(256) void k_colsum(const float* __restrict__ x2,
                                                float* colsum, int n) {
    __shared__ float lds[256];
    int tid = threadIdx.x;
    int f = tid & 127;
    int half = tid >> 7;
    float acc = 0.f;
    for (int r = blockIdx.x * 2 + half; r < n; r += gridDim.x * 2)
        acc += x2[(size_t)r * FEAT + f];
    lds[tid] = acc;
    __syncthreads();
    if (tid < 128) atomicAdd(&colsum[f], lds[f] + lds[f + 128]);
}

// ---------------- final: (colsum/n) @ Wc + bc ----------------
__global__ void k_final(const float* __restrict__ colsum, const float* __restrict__ Wc,
                        const float* __restrict__ bc, float* out, int n) {
    int c = threadIdx.x;
    if (c < N_CLS) {
        float acc = 0.f;
        for (int f = 0; f < FEAT; ++f) acc += colsum[f] * Wc[f * N_CLS + c];
        out[c] = acc / (float)n + bc[c];
    }
}

extern "C" void kernel_launch(void* const* d_in, const int* in_sizes, int n_in,
                              void* d_out, int out_size, void* d_ws, size_t ws_size,
                              hipStream_t stream) {
    const float* x   = (const float*)d_in[0];
    const int*   ei  = (const int*)d_in[1];   // harness passes integer inputs as int32
    const float* W1  = (const float*)d_in[2];
    const float* b1  = (const float*)d_in[3];
    const float* Ws1 = (const float*)d_in[4];
    const float* bs1 = (const float*)d_in[5];
    const float* W2  = (const float*)d_in[6];
    const float* b2  = (const float*)d_in[7];
    const float* Ws2 = (const float*)d_in[8];
    const float* bs2 = (const float*)d_in[9];
    const float* Wc  = (const float*)d_in[10];
    const float* bc  = (const float*)d_in[11];
    float* out = (float*)d_out;

    const int n = in_sizes[0] / FEAT;
    const int E = in_sizes[1] / 2;
    const int* src = ei;
    const int* dst = ei + E;

    const int nb = (n + 255) / 256;  // 196 blocks (<= 256 for k_bscan)

    // workspace carve-out (~55 MB total)
    char* w = (char*)d_ws;
    auto alloc = [&](size_t bytes) -> void* {
        void* p = (void*)w;
        w += (bytes + 255) & ~(size_t)255;
        return p;
    };
    int*   deg    = (int*)alloc((size_t)n * 4);
    int*   off    = (int*)alloc(((size_t)n + 1) * 4);
    int*   cursor = (int*)alloc((size_t)n * 4);
    int*   csr    = (int*)alloc((size_t)E * 4);
    float* dinv   = (float*)alloc((size_t)n * 4);
    float* colsum = (float*)alloc(FEAT * 4);
    int*   bsum   = (int*)alloc((size_t)nb * 4);
    float* A = (float*)alloc((size_t)n * FEAT * 4);  // hs (both layers)
    float* B = (float*)alloc((size_t)n * FEAT * 4);  // xs1 -> out1 -> xs2 -> out2

    // graph prep
    k_init<<<nb, 256, 0, stream>>>(deg, colsum, n);
    k_hist<<<(E + 255) / 256, 256, 0, stream>>>(dst, deg, E);
    k_bsum<<<nb, 256, 0, stream>>>(deg, bsum, n);
    k_bscan<<<1, 256, 0, stream>>>(bsum, nb);
    k_write<<<nb, 256, 0, stream>>>(deg, bsum, off, cursor, dinv, n, E);
    k_fill<<<(E + 255) / 256, 256, 0, stream>>>(src, dst, cursor, csr, E);

    int gemm_grid = (n + 63) / 64;
    int agg_grid  = (n + 3) / 4;

    // layer 1
    k_gemm<<<gemm_grid, 256, 0, stream>>>(x, W1, Ws1, b1, bs1, dinv, A, B, n);
    k_agg<<<agg_grid, 256, 0, stream>>>(A, B, dinv, off, csr, n);
    // layer 2 (xs written in-place into B; safe per-block row ownership)
    k_gemm<<<gemm_grid, 256, 0, stream>>>(B, W2, Ws2, b2, bs2, dinv, A, B, n);
    k_agg<<<agg_grid, 256, 0, stream>>>(A, B, dinv, off, csr, n);

    // readout
    k_colsum<<<512, 256, 0, stream>>>(B, colsum, n);
    k_final<<<1, 64, 0, stream>>>(colsum, Wc, bc, out, n);
}

// Round 5
// 448.143 us; speedup vs baseline: 1.3913x; 1.0834x over previous
//
#include <hip/hip_runtime.h>

#define FEAT 128
#define N_CLS 10

// ---------------- init: deg=1 (self loop), colsum=0 ----------------
__global__ void k_init(int* deg, float* colsum, int n) {
    int i = blockIdx.x * blockDim.x + threadIdx.x;
    if (i < n) deg[i] = 1;
    if (i < FEAT) colsum[i] = 0.f;
}

// ---------------- histogram of dst (int32 edge list) ----------------
__global__ void k_hist(const int* __restrict__ dst, int* deg, int E) {
    int e = blockIdx.x * blockDim.x + threadIdx.x;
    if (e < E) atomicAdd(&deg[dst[e]], 1);
}

// ---------------- hierarchical scan, stage 1: per-block sums of (deg-1) ----------------
__global__ __launch_bounds__(256) void k_bsum(const int* __restrict__ deg,
                                              int* __restrict__ bsum, int n) {
    int i = blockIdx.x * 256 + threadIdx.x;
    int v = (i < n) ? (deg[i] - 1) : 0;
    #pragma unroll
    for (int d = 32; d; d >>= 1) v += __shfl_down(v, d, 64);
    __shared__ int ws[4];
    int lane = threadIdx.x & 63, wid = threadIdx.x >> 6;
    if (lane == 0) ws[wid] = v;
    __syncthreads();
    if (threadIdx.x == 0) bsum[blockIdx.x] = ws[0] + ws[1] + ws[2] + ws[3];
}

// ---------------- stage 2: exclusive scan of block sums (nb <= 256) ----------------
__global__ __launch_bounds__(256) void k_bscan(int* bsum, int nb) {
    __shared__ int lds[256];
    int t = threadIdx.x;
    int v = (t < nb) ? bsum[t] : 0;
    lds[t] = v;
    __syncthreads();
    #pragma unroll
    for (int d = 1; d < 256; d <<= 1) {
        int u = (t >= d) ? lds[t - d] : 0;
        __syncthreads();
        lds[t] += u;
        __syncthreads();
    }
    if (t < nb) bsum[t] = lds[t] - v;  // exclusive prefix
}

// ---------------- stage 3: block-local scan + offset -> off/cursor/dinv ----------------
__global__ __launch_bounds__(256) void k_write(const int* __restrict__ deg,
                                               const int* __restrict__ bsum,
                                               int* off, int* cursor, float* dinv,
                                               int n, int E) {
    __shared__ int lds[256];
    int t = threadIdx.x;
    int i = blockIdx.x * 256 + t;
    int v = (i < n) ? (deg[i] - 1) : 0;
    lds[t] = v;
    __syncthreads();
    #pragma unroll
    for (int d = 1; d < 256; d <<= 1) {
        int u = (t >= d) ? lds[t - d] : 0;
        __syncthreads();
        lds[t] += u;
        __syncthreads();
    }
    if (i < n) {
        int o = bsum[blockIdx.x] + (lds[t] - v);
        off[i] = o;
        cursor[i] = o;
        dinv[i] = rsqrtf((float)deg[i]);
    }
    if (i == n - 1) off[n] = E;  // every edge lands in [0,n): total incoming == E
}

// ---------------- fill CSR (by dst), store src ----------------
__global__ void k_fill(const int* __restrict__ src, const int* __restrict__ dst,
                       int* cursor, int* csr, int E) {
    int e = blockIdx.x * blockDim.x + threadIdx.x;
    if (e < E) {
        int d = dst[e];
        int pos = atomicAdd(&cursor[d], 1);
        csr[pos] = src[e];
    }
}

// ---------------- fused dual GEMM: hs=(x@W)*dinv, xs=x@Ws+b+bs ----------------
// block 256, 64-row tile; per thread 8 rows x (4 W-cols + 4 Ws-cols)
// k-loop unrolled x4 with float4 LDS fragment loads (ds_read_b128, broadcast).
// NOTE: xs may alias x (in-place): each block stages its 64 rows to LDS before
// any global write, and blocks only write their own rows.
__global__ __launch_bounds__(256) void k_gemm(
    const float* x, const float* __restrict__ W,
    const float* __restrict__ Ws, const float* __restrict__ b,
    const float* __restrict__ bs, const float* __restrict__ dinv,
    float* __restrict__ hs, float* xs, int n) {
    __shared__ float x_lds[64 * FEAT];
    int tid = threadIdx.x;
    int row0 = blockIdx.x * 64;

    // stage x tile (coalesced float4)
    int c4 = (tid & 31) * 4;
    int rl = tid >> 5;  // 0..7
    #pragma unroll
    for (int p = 0; p < 8; ++p) {
        int r = rl + p * 8;
        float4 v = make_float4(0.f, 0.f, 0.f, 0.f);
        if (row0 + r < n) v = *(const float4*)&x[(size_t)(row0 + r) * FEAT + c4];
        *(float4*)&x_lds[r * FEAT + c4] = v;
    }
    __syncthreads();

    int ct = tid & 31;  // cols ct*4 .. ct*4+3
    int rt = tid >> 5;  // rows rt*8 .. rt*8+7
    float accW[8][4], accS[8][4];
    #pragma unroll
    for (int i = 0; i < 8; ++i)
        #pragma unroll
        for (int j = 0; j < 4; ++j) { accW[i][j] = 0.f; accS[i][j] = 0.f; }

    const float* Wp = W + ct * 4;
    const float* Sp = Ws + ct * 4;
    for (int k = 0; k < FEAT; k += 4) {
        float4 a[8];
        #pragma unroll
        for (int i = 0; i < 8; ++i)
            a[i] = *(const float4*)&x_lds[(rt * 8 + i) * FEAT + k];
        #pragma unroll
        for (int kk = 0; kk < 4; ++kk) {
            float4 bw = *(const float4*)&Wp[(size_t)(k + kk) * FEAT];
            float4 bv = *(const float4*)&Sp[(size_t)(k + kk) * FEAT];
            #pragma unroll
            for (int i = 0; i < 8; ++i) {
                float av = (&a[i].x)[kk];
                accW[i][0] += av * bw.x; accW[i][1] += av * bw.y;
                accW[i][2] += av * bw.z; accW[i][3] += av * bw.w;
                accS[i][0] += av * bv.x; accS[i][1] += av * bv.y;
                accS[i][2] += av * bv.z; accS[i][3] += av * bv.w;
            }
        }
    }

    float4 bb  = *(const float4*)&b[ct * 4];
    float4 bb2 = *(const float4*)&bs[ct * 4];
    float4 bias = make_float4(bb.x + bb2.x, bb.y + bb2.y, bb.z + bb2.z, bb.w + bb2.w);
    #pragma unroll
    for (int i = 0; i < 8; ++i) {
        int r = row0 + rt * 8 + i;
        if (r < n) {
            float dv = dinv[r];
            size_t o = (size_t)r * FEAT + ct * 4;
            float4 o1 = make_float4(accW[i][0] * dv, accW[i][1] * dv,
                                    accW[i][2] * dv, accW[i][3] * dv);
            *(float4*)&hs[o] = o1;
            float4 o2 = make_float4(accS[i][0] + bias.x, accS[i][1] + bias.y,
                                    accS[i][2] + bias.z, accS[i][3] + bias.w);
            *(float4*)&xs[o] = o2;
        }
    }
}

// ---------------- aggregation + skip + bias + relu (in place in xs) ----------------
// one wave per node, float2 per lane; 4-way unrolled gather for MLP
__global__ __launch_bounds__(256) void k_agg(
    const float* __restrict__ hs, float* __restrict__ xs,
    const float* __restrict__ dinv, const int* __restrict__ off,
    const int* __restrict__ csr, int n) {
    int wave = (blockIdx.x * 256 + threadIdx.x) >> 6;
    int lane = threadIdx.x & 63;
    if (wave >= n) return;
    int node = wave;
    size_t fo = (size_t)lane * 2;
    size_t o = (size_t)node * FEAT + fo;
    float2 a0 = *(const float2*)&hs[o];  // self loop contribution (pre-scaled)
    float2 a1 = make_float2(0.f, 0.f);
    float2 a2 = make_float2(0.f, 0.f);
    float2 a3 = make_float2(0.f, 0.f);
    int s = off[node], e = off[node + 1];
    int j = s;
    for (; j + 4 <= e; j += 4) {
        int u0 = csr[j], u1 = csr[j + 1], u2 = csr[j + 2], u3 = csr[j + 3];
        float2 v0 = *(const float2*)&hs[(size_t)u0 * FEAT + fo];
        float2 v1 = *(const float2*)&hs[(size_t)u1 * FEAT + fo];
        float2 v2 = *(const float2*)&hs[(size_t)u2 * FEAT + fo];
        float2 v3 = *(const float2*)&hs[(size_t)u3 * FEAT + fo];
        a0.x += v0.x; a0.y += v0.y;
        a1.x += v1.x; a1.y += v1.y;
        a2.x += v2.x; a2.y += v2.y;
        a3.x += v3.x; a3.y += v3.y;
    }
    for (; j < e; ++j) {
        int u = csr[j];
        float2 v = *(const float2*)&hs[(size_t)u * FEAT + fo];
        a0.x += v.x; a0.y += v.y;
    }
    float2 acc;
    acc.x = (a0.x + a1.x) + (a2.x + a3.x);
    acc.y = (a0.y + a1.y) + (a2.y + a3.y);
    float dv = dinv[node];
    float2 sk = *(const float2*)&xs[o];
    float2 out;
    out.x = fmaxf(fmaf(acc.x, dv, sk.x), 0.f);
    out.y = fmaxf(fmaf(acc.y, dv, sk.y), 0.f);
    *(float2*)&xs[o] = out;
}

// ---------------- column sum (block-reduced, atomics on 128 addrs) ----------------
__global__ __launch_bounds__(256) void k_colsum(const float* __restrict__ x2,
                                                float* colsum, int n) {
    __shared__ float lds[256];
    int tid = threadIdx.x;
    int f = tid & 127;
    int half = tid >> 7;
    float acc = 0.f;
    for (int r = blockIdx.x * 2 + half; r < n; r += gridDim.x * 2)
        acc += x2[(size_t)r * FEAT + f];
    lds[tid] = acc;
    __syncthreads();
    if (tid < 128) atomicAdd(&colsum[f], lds[f] + lds[f + 128]);
}

// ---------------- final: (colsum/n) @ Wc + bc ----------------
__global__ void k_final(const float* __restrict__ colsum, const float* __restrict__ Wc,
                        const float* __restrict__ bc, float* out, int n) {
    int c = threadIdx.x;
    if (c < N_CLS) {
        float acc = 0.f;
        for (int f = 0; f < FEAT; ++f) acc += colsum[f] * Wc[f * N_CLS + c];
        out[c] = acc / (float)n + bc[c];
    }
}

extern "C" void kernel_launch(void* const* d_in, const int* in_sizes, int n_in,
                              void* d_out, int out_size, void* d_ws, size_t ws_size,
                              hipStream_t stream) {
    const float* x   = (const float*)d_in[0];
    const int*   ei  = (const int*)d_in[1];   // harness passes integer inputs as int32
    const float* W1  = (const float*)d_in[2];
    const float* b1  = (const float*)d_in[3];
    const float* Ws1 = (const float*)d_in[4];
    const float* bs1 = (const float*)d_in[5];
    const float* W2  = (const float*)d_in[6];
    const float* b2  = (const float*)d_in[7];
    const float* Ws2 = (const float*)d_in[8];
    const float* bs2 = (const float*)d_in[9];
    const float* Wc  = (const float*)d_in[10];
    const float* bc  = (const float*)d_in[11];
    float* out = (float*)d_out;

    const int n = in_sizes[0] / FEAT;
    const int E = in_sizes[1] / 2;
    const int* src = ei;
    const int* dst = ei + E;

    const int nb = (n + 255) / 256;  // 196 blocks (<= 256 for k_bscan)

    // workspace carve-out (~55 MB total)
    char* w = (char*)d_ws;
    auto alloc = [&](size_t bytes) -> void* {
        void* p = (void*)w;
        w += (bytes + 255) & ~(size_t)255;
        return p;
    };
    int*   deg    = (int*)alloc((size_t)n * 4);
    int*   off    = (int*)alloc(((size_t)n + 1) * 4);
    int*   cursor = (int*)alloc((size_t)n * 4);
    int*   csr    = (int*)alloc((size_t)E * 4);
    float* dinv   = (float*)alloc((size_t)n * 4);
    float* colsum = (float*)alloc(FEAT * 4);
    int*   bsum   = (int*)alloc((size_t)nb * 4);
    float* A = (float*)alloc((size_t)n * FEAT * 4);  // hs (both layers)
    float* B = (float*)alloc((size_t)n * FEAT * 4);  // xs1 -> out1 -> xs2 -> out2

    // graph prep
    k_init<<<nb, 256, 0, stream>>>(deg, colsum, n);
    k_hist<<<(E + 255) / 256, 256, 0, stream>>>(dst, deg, E);
    k_bsum<<<nb, 256, 0, stream>>>(deg, bsum, n);
    k_bscan<<<1, 256, 0, stream>>>(bsum, nb);
    k_write<<<nb, 256, 0, stream>>>(deg, bsum, off, cursor, dinv, n, E);
    k_fill<<<(E + 255) / 256, 256, 0, stream>>>(src, dst, cursor, csr, E);

    int gemm_grid = (n + 63) / 64;
    int agg_grid  = (n + 3) / 4;

    // layer 1
    k_gemm<<<gemm_grid, 256, 0, stream>>>(x, W1, Ws1, b1, bs1, dinv, A, B, n);
    k_agg<<<agg_grid, 256, 0, stream>>>(A, B, dinv, off, csr, n);
    // layer 2 (xs written in-place into B; safe per-block row ownership)
    k_gemm<<<gemm_grid, 256, 0, stream>>>(B, W2, Ws2, b2, bs2, dinv, A, B, n);
    k_agg<<<agg_grid, 256, 0, stream>>>(A, B, dinv, off, csr, n);

    // readout
    k_colsum<<<512, 256, 0, stream>>>(B, colsum, n);
    k_final<<<1, 64, 0, stream>>>(colsum, Wc, bc, out, n);
}